// Round 1
// baseline (260.523 us; speedup 1.0000x reference)
//
#include <hip/hip_runtime.h>
#include <math.h>

#define BB 64
#define NN 8192
#define TOTAL_W 9356

// Per-layer block in tnw: W (din*dout), bias (dout), w_scale (dout),
// b_scale (dout), w_shift (dout).
template<int DIN, int DOUT, bool ACT>
__device__ __forceinline__ void layer(const float* __restrict__ wb,
                                      const float* __restrict__ h_in,
                                      float* __restrict__ h_out,
                                      float ctx) {
  const float* __restrict__ W    = wb;                 // DIN*DOUT
  const float* __restrict__ bias = wb + DIN * DOUT;
  const float* __restrict__ wsc  = bias + DOUT;
  const float* __restrict__ bsc  = wsc + DOUT;
  const float* __restrict__ wsh  = bsc + DOUT;

  float acc[DOUT];
#pragma unroll
  for (int e = 0; e < DOUT; ++e) acc[e] = bias[e];

#pragma unroll
  for (int d = 0; d < DIN; ++d) {
    float hd = h_in[d];
#pragma unroll
    for (int e = 0; e < DOUT; ++e)
      acc[e] = fmaf(hd, W[d * DOUT + e], acc[e]);   // weight is wave-uniform -> SGPR operand
  }

#pragma unroll
  for (int e = 0; e < DOUT; ++e) {
    float z = fmaf(ctx, wsc[e], bsc[e]);
    float s = 1.0f / (1.0f + __expf(-z));           // sigmoid
    float v = fmaf(ctx, wsh[e], s * acc[e]);        // scale*dx + ctx*w_shift
    if (ACT) {
      // softplus, numerically stable: max(v,0) + log(1 + exp(-|v|))
      float a = fabsf(v);
      v = fmaxf(v, 0.0f) + __logf(1.0f + __expf(-a));
    }
    h_out[e] = v;
  }
}

__global__ __launch_bounds__(256)
void ode_hypernet_kernel(const float* __restrict__ context,
                         const float* __restrict__ y,
                         const float* __restrict__ tnw,
                         float* __restrict__ out) {
  const int b = blockIdx.y;
  const int n = blockIdx.x * blockDim.x + threadIdx.x;

  const float* __restrict__ wb = tnw + (size_t)b * TOTAL_W;

  const float ctx = context[(size_t)b * NN + n];
  const size_t ybase = ((size_t)b * NN + n) * 3;

  float h0[3];
  h0[0] = y[ybase + 0];
  h0[1] = y[ybase + 1];
  h0[2] = y[ybase + 2];

  float h1[64], h2[64];
  layer<3, 64, true>(wb, h0, h1, ctx);                      // off 0    .. 448
  layer<64, 64, true>(wb + 448, h1, h2, ctx);               // off 448  .. 4800
  layer<64, 64, true>(wb + 4800, h2, h1, ctx);              // off 4800 .. 9152
  float ho[3];
  layer<64, 3, false>(wb + 9152, h1, ho, ctx);              // off 9152 .. 9356

  out[ybase + 0] = ho[0];
  out[ybase + 1] = ho[1];
  out[ybase + 2] = ho[2];
}

extern "C" void kernel_launch(void* const* d_in, const int* in_sizes, int n_in,
                              void* d_out, int out_size, void* d_ws, size_t ws_size,
                              hipStream_t stream) {
  const float* context = (const float*)d_in[0];   // (64, 8192)
  const float* y       = (const float*)d_in[1];   // (64, 8192, 3)
  const float* tnw     = (const float*)d_in[2];   // (64, 9356)
  float* out           = (float*)d_out;           // (64, 8192, 3)

  dim3 grid(NN / 256, BB, 1);
  dim3 block(256, 1, 1);
  ode_hypernet_kernel<<<grid, block, 0, stream>>>(context, y, tnw, out);
}

// Round 2
// 234.633 us; speedup vs baseline: 1.1103x; 1.1103x over previous
//
#include <hip/hip_runtime.h>
#include <math.h>

#define BB 64
#define NN 8192
#define TOTAL_W 9356

typedef float v2f __attribute__((ext_vector_type(2)));
typedef float v4f __attribute__((ext_vector_type(4)));

// Layer with DOUT % 4 == 0. Weights come from LDS (wave-uniform broadcast
// reads -> no bank conflicts). Row-major W[d][e], d-outer loop, packed
// float2 accumulators so LLVM can emit v_pk_fma_f32 (2 MACs/instr).
template<int DIN, int DOUT, bool ACT>
__device__ __forceinline__ void layer_lds(const float* __restrict__ wb,
                                          const float* __restrict__ h_in,
                                          float* __restrict__ h_out,
                                          float ctx) {
  v2f acc[DOUT / 2];
  const v4f* __restrict__ B4 = (const v4f*)(wb + DIN * DOUT);
#pragma unroll
  for (int q = 0; q < DOUT / 4; ++q) {
    v4f bq = B4[q];
    acc[2 * q + 0] = (v2f){bq.x, bq.y};
    acc[2 * q + 1] = (v2f){bq.z, bq.w};
  }

#pragma unroll
  for (int d = 0; d < DIN; ++d) {
    const float hd = h_in[d];
    const v2f hdv = (v2f){hd, hd};
    const v4f* __restrict__ Wd = (const v4f*)(wb + d * DOUT);
#pragma unroll
    for (int q = 0; q < DOUT / 4; ++q) {
      v4f w = Wd[q];  // one ds_read_b128 (broadcast)
      acc[2 * q + 0] = __builtin_elementwise_fma((v2f){w.x, w.y}, hdv, acc[2 * q + 0]);
      acc[2 * q + 1] = __builtin_elementwise_fma((v2f){w.z, w.w}, hdv, acc[2 * q + 1]);
    }
  }

  const float* __restrict__ wsc = wb + DIN * DOUT + DOUT;
  const float* __restrict__ bsc = wsc + DOUT;
  const float* __restrict__ wsh = bsc + DOUT;
#pragma unroll
  for (int e = 0; e < DOUT; ++e) {
    float z = fmaf(ctx, wsc[e], bsc[e]);
    float s = 1.0f / (1.0f + __expf(-z));  // sigmoid
    float ae = (e & 1) ? acc[e / 2].y : acc[e / 2].x;
    float v = fmaf(ctx, wsh[e], s * ae);
    if (ACT) {  // softplus: max(v,0) + log(1+exp(-|v|))
      float a = fabsf(v);
      v = fmaxf(v, 0.0f) + __logf(1.0f + __expf(-a));
    }
    h_out[e] = v;
  }
}

// Final layer: DIN=64, DOUT=3, sigmoid-FiLM only (no softplus).
__device__ __forceinline__ void layer_last(const float* __restrict__ wb,
                                           const float* __restrict__ h_in,
                                           float* __restrict__ h_out,
                                           float ctx) {
  const int DIN = 64, DOUT = 3;
  float acc[3];
  const float* __restrict__ bias = wb + DIN * DOUT;
#pragma unroll
  for (int e = 0; e < 3; ++e) acc[e] = bias[e];
#pragma unroll
  for (int d = 0; d < DIN; ++d) {
    const float hd = h_in[d];
#pragma unroll
    for (int e = 0; e < 3; ++e) acc[e] = fmaf(hd, wb[d * 3 + e], acc[e]);
  }
  const float* __restrict__ wsc = bias + 3;
  const float* __restrict__ bsc = wsc + 3;
  const float* __restrict__ wsh = bsc + 3;
#pragma unroll
  for (int e = 0; e < 3; ++e) {
    float z = fmaf(ctx, wsc[e], bsc[e]);
    float s = 1.0f / (1.0f + __expf(-z));
    h_out[e] = fmaf(ctx, wsh[e], s * acc[e]);
  }
}

__global__ __launch_bounds__(256)
void ode_hypernet_kernel(const float* __restrict__ context,
                         const float* __restrict__ y,
                         const float* __restrict__ tnw,
                         float* __restrict__ out) {
  __shared__ float wl[TOTAL_W];  // 37,424 B

  const int b = blockIdx.y;
  const int tid = threadIdx.x;

  // Cooperative stage: TOTAL_W = 9356 = 2339 float4s (16B-aligned per b).
  {
    const v4f* __restrict__ src = (const v4f*)(tnw + (size_t)b * TOTAL_W);
    v4f* dst = (v4f*)wl;
#pragma unroll 1
    for (int i = tid; i < TOTAL_W / 4; i += 256) dst[i] = src[i];
  }
  __syncthreads();

  const int n = blockIdx.x * blockDim.x + tid;
  const float ctx = context[(size_t)b * NN + n];
  const size_t ybase = ((size_t)b * NN + n) * 3;

  float h0[3];
  h0[0] = y[ybase + 0];
  h0[1] = y[ybase + 1];
  h0[2] = y[ybase + 2];

  float h1[64], h2[64];
  layer_lds<3, 64, true>(wl, h0, h1, ctx);          // off 0    .. 448
  layer_lds<64, 64, true>(wl + 448, h1, h2, ctx);   // off 448  .. 4800
  layer_lds<64, 64, true>(wl + 4800, h2, h1, ctx);  // off 4800 .. 9152
  float ho[3];
  layer_last(wl + 9152, h1, ho, ctx);               // off 9152 .. 9356

  out[ybase + 0] = ho[0];
  out[ybase + 1] = ho[1];
  out[ybase + 2] = ho[2];
}

extern "C" void kernel_launch(void* const* d_in, const int* in_sizes, int n_in,
                              void* d_out, int out_size, void* d_ws, size_t ws_size,
                              hipStream_t stream) {
  const float* context = (const float*)d_in[0];  // (64, 8192)
  const float* y       = (const float*)d_in[1];  // (64, 8192, 3)
  const float* tnw     = (const float*)d_in[2];  // (64, 9356)
  float* out           = (float*)d_out;          // (64, 8192, 3)

  dim3 grid(NN / 256, BB, 1);
  dim3 block(256, 1, 1);
  ode_hypernet_kernel<<<grid, block, 0, stream>>>(context, y, tnw, out);
}

// Round 4
// 61.326 us; speedup vs baseline: 4.2482x; 3.8260x over previous
//
#include <hip/hip_runtime.h>
#include <math.h>

#define BB 64
#define NN 8192
#define TOTAL_W 9356

typedef _Float16 f16x8 __attribute__((ext_vector_type(8)));
typedef float f32x4 __attribute__((ext_vector_type(4)));
typedef unsigned int u32x2 __attribute__((ext_vector_type(2)));

#define L2E 1.44269504088896340736f
#define LN2 0.6931471805599453f

// ---- LDS layout (bytes) ----
#define W0_OFF   0                      // W0pack[64] f32x4: {W0[0][f],W0[1][f],W0[2][f],0}
#define FILM_OFF 1024                   // film[4][64] f32x4: {wsc*log2e, bsc*log2e, wsh, bias}
#define A1_OFF   (FILM_OFF + 4096)     // A-frags L1: [m][t][lane] f16x8 = 8192 B
#define A2_OFF   (A1_OFF + 8192)       // A-frags L2
#define A3_OFF   (A2_OFF + 8192)       // A-frags L3: [t][lane] f16x8 = 2048 B
#define ACT_OFF  (A3_OFF + 2048)       // Act[128 pts][16 slots][8B], XOR-swizzled
#define LDS_BYTES (ACT_OFF + 128*128)  // 39936

#define MFMA16(a, b, c) __builtin_amdgcn_mfma_f32_16x16x32_f16(a, b, c, 0, 0, 0)

// FiLM (+optional softplus) on one D-quad, pack to f16, store 8B into Act.
// f = 16*m + 4*g + j ; Act slot = 4*m + g, position = slot ^ (pt & 14).
template<bool SP>
__device__ __forceinline__ void film_pack_store(unsigned char* smem, int Lf, int m, int g,
                                                float ctx, int pt, f32x4 acc) {
  float sp[4];
#pragma unroll
  for (int j = 0; j < 4; ++j) {
    f32x4 fm = *(const f32x4*)(smem + FILM_OFF + (((Lf * 64) + 16 * m + 4 * g + j) << 4));
    float pre = acc[j] + fm.w;                                   // + bias
    float z = fmaf(ctx, fm.x, fm.y);                             // (ctx*wsc + bsc)*log2e
    float s = __builtin_amdgcn_rcpf(1.0f + __builtin_amdgcn_exp2f(-z));  // sigmoid
    float v = fmaf(ctx, fm.z, s * pre);                          // scale*dx + ctx*wshift
    if (SP) {                                                    // softplus = ln(1+e^v)
      float u = __builtin_amdgcn_exp2f(v * L2E);
      v = LN2 * __builtin_amdgcn_logf(1.0f + u);                 // amdgcn_logf = log2
    }
    sp[j] = v;
  }
  auto p01 = __builtin_amdgcn_cvt_pkrtz(sp[0], sp[1]);
  auto p23 = __builtin_amdgcn_cvt_pkrtz(sp[2], sp[3]);
  u32x2 w;
  w.x = __builtin_bit_cast(unsigned int, p01);
  w.y = __builtin_bit_cast(unsigned int, p23);
  int slot = 4 * m + g;
  *(u32x2*)(smem + ACT_OFF + pt * 128 + (((slot ^ (pt & 14))) << 3)) = w;
}

__global__ __launch_bounds__(256)
void ode_hypernet_kernel(const float* __restrict__ context,
                         const float* __restrict__ y,
                         const float* __restrict__ tnw,
                         float* __restrict__ out) {
  __shared__ __align__(16) unsigned char smem[LDS_BYTES];
  const int b = blockIdx.y;
  const int tid = threadIdx.x;
  const float* __restrict__ wb = tnw + (size_t)b * TOTAL_W;

  // ---------- staging ----------
  if (tid < 64) {  // W0pack: W0[d][f] = wb[d*64+f]
    f32x4 v = {wb[tid], wb[64 + tid], wb[128 + tid], 0.f};
    *(f32x4*)(smem + W0_OFF + (tid << 4)) = v;
  }
  {  // film params; layer l: bias@bo, wsc@bo+d, bsc@bo+2d, wsh@bo+3d
    const int biaso[4] = {192, 4544, 8896, 9344};
    const int dim[4] = {64, 64, 64, 3};
#pragma unroll
    for (int l = 0; l < 4; ++l) {
      if (tid < 64) {
        f32x4 v = {0.f, 0.f, 0.f, 0.f};
        if (tid < dim[l]) {
          int bo = biaso[l], d = dim[l];
          v.x = wb[bo + d + tid] * L2E;
          v.y = wb[bo + 2 * d + tid] * L2E;
          v.z = wb[bo + 3 * d + tid];
          v.w = wb[bo + tid];
        }
        *(f32x4*)(smem + FILM_OFF + ((l * 64 + tid) << 4)) = v;
      }
    }
  }
  // A-fragments for L1/L2 (A = W^T, 16x32 tiles): row r = m*128 + t*64 + lane
  // lane holds A[row=lane&15][k=8*(lane>>4)+i] -> W[f_in][f_out], f_out=16m+(lane&15),
  // f_in = 32t + 8*(lane>>4) + i
#pragma unroll
  for (int L = 0; L < 2; ++L) {
    const int woff = L ? 4800 : 448;
    const int aoff = L ? A2_OFF : A1_OFF;
    for (int r = tid; r < 512; r += 256) {
      int lane_r = r & 63;
      int t = (r >> 6) & 1;
      int m = r >> 7;
      int f_out = 16 * m + (lane_r & 15);
      int f_in0 = 32 * t + 8 * (lane_r >> 4);
      f16x8 h;
#pragma unroll
      for (int i = 0; i < 8; ++i) h[i] = (_Float16)wb[woff + (f_in0 + i) * 64 + f_out];
      *(f16x8*)(smem + aoff + r * 16) = h;
    }
  }
  if (tid < 128) {  // A3: W3[f_in][3], rows>=3 zero
    int lane_r = tid & 63;
    int t = tid >> 6;
    int f_out = lane_r & 15;
    int f_in0 = 32 * t + 8 * (lane_r >> 4);
    f16x8 h;
#pragma unroll
    for (int i = 0; i < 8; ++i)
      h[i] = (f_out < 3) ? (_Float16)wb[9152 + (f_in0 + i) * 3 + f_out] : (_Float16)0.f;
    *(f16x8*)(smem + A3_OFF + tid * 16) = h;
  }
  __syncthreads();

  // ---------- per-wave main ----------
  const int lane = tid & 63;
  const int wid = tid >> 6;
  const int g = lane >> 4;
  const int col = lane & 15;
  const int pt0 = wid * 32 + col;      // block-local point ids for the two B-tiles
  const int pt1 = pt0 + 16;
  const int n0 = blockIdx.x * 128 + pt0;
  const int n1 = n0 + 16;

  const float ctx0 = context[(size_t)b * NN + n0];
  const float ctx1 = context[(size_t)b * NN + n1];
  const size_t yb0 = ((size_t)b * NN + n0) * 3;
  const size_t yb1 = ((size_t)b * NN + n1) * 3;
  const float y00 = y[yb0], y01 = y[yb0 + 1], y02 = y[yb0 + 2];
  const float y10 = y[yb1], y11 = y[yb1 + 1], y12 = y[yb1 + 2];

  // ----- layer 0 (3 -> 64) on VALU, same output layout as MFMA D -----
#pragma unroll
  for (int m = 0; m < 4; ++m) {
    f32x4 c0, c1;
#pragma unroll
    for (int j = 0; j < 4; ++j) {
      f32x4 w0 = *(const f32x4*)(smem + W0_OFF + ((16 * m + 4 * g + j) << 4));
      c0[j] = fmaf(y00, w0.x, fmaf(y01, w0.y, y02 * w0.z));
      c1[j] = fmaf(y10, w0.x, fmaf(y11, w0.y, y12 * w0.z));
    }
    film_pack_store<true>(smem, 0, m, g, ctx0, pt0, c0);
    film_pack_store<true>(smem, 0, m, g, ctx1, pt1, c1);
  }

  const int msk0 = pt0 & 14, msk1 = pt1 & 14;

  // ----- layers 1,2 (64 -> 64) on MFMA -----
#pragma unroll
  for (int L = 1; L <= 2; ++L) {
    const int aoff = (L == 1) ? A1_OFF : A2_OFF;
    // B fragments (current activations), k = 32t + 8g + i
    f16x8 B00 = *(const f16x8*)(smem + ACT_OFF + pt0 * 128 + (((2 * g) ^ msk0) << 3));
    f16x8 B01 = *(const f16x8*)(smem + ACT_OFF + pt0 * 128 + (((8 + 2 * g) ^ msk0) << 3));
    f16x8 B10 = *(const f16x8*)(smem + ACT_OFF + pt1 * 128 + (((2 * g) ^ msk1) << 3));
    f16x8 B11 = *(const f16x8*)(smem + ACT_OFF + pt1 * 128 + (((8 + 2 * g) ^ msk1) << 3));
#pragma unroll
    for (int m = 0; m < 4; ++m) {
      f16x8 a0 = *(const f16x8*)(smem + aoff + ((m * 2 + 0) * 64 + lane) * 16);
      f16x8 a1 = *(const f16x8*)(smem + aoff + ((m * 2 + 1) * 64 + lane) * 16);
      f32x4 c0 = {0.f, 0.f, 0.f, 0.f};
      c0 = MFMA16(a0, B00, c0);
      c0 = MFMA16(a1, B01, c0);
      f32x4 c1 = {0.f, 0.f, 0.f, 0.f};
      c1 = MFMA16(a0, B10, c1);
      c1 = MFMA16(a1, B11, c1);
      film_pack_store<true>(smem, L, m, g, ctx0, pt0, c0);
      film_pack_store<true>(smem, L, m, g, ctx1, pt1, c1);
    }
  }

  // ----- layer 3 (64 -> 3) on MFMA, FiLM only, store -----
  {
    f16x8 B00 = *(const f16x8*)(smem + ACT_OFF + pt0 * 128 + (((2 * g) ^ msk0) << 3));
    f16x8 B01 = *(const f16x8*)(smem + ACT_OFF + pt0 * 128 + (((8 + 2 * g) ^ msk0) << 3));
    f16x8 B10 = *(const f16x8*)(smem + ACT_OFF + pt1 * 128 + (((2 * g) ^ msk1) << 3));
    f16x8 B11 = *(const f16x8*)(smem + ACT_OFF + pt1 * 128 + (((8 + 2 * g) ^ msk1) << 3));
    f16x8 a0 = *(const f16x8*)(smem + A3_OFF + (0 * 64 + lane) * 16);
    f16x8 a1 = *(const f16x8*)(smem + A3_OFF + (1 * 64 + lane) * 16);
    f32x4 c0 = {0.f, 0.f, 0.f, 0.f};
    c0 = MFMA16(a0, B00, c0);
    c0 = MFMA16(a1, B01, c0);
    f32x4 c1 = {0.f, 0.f, 0.f, 0.f};
    c1 = MFMA16(a0, B10, c1);
    c1 = MFMA16(a1, B11, c1);
#pragma unroll
    for (int p = 0; p < 2; ++p) {
      f32x4 c = p ? c1 : c0;
      float ctx = p ? ctx1 : ctx0;
      int n = p ? n1 : n0;
#pragma unroll
      for (int j = 0; j < 3; ++j) {  // valid rows f = 4g+j < 3 -> g==0 only
        f32x4 fm = *(const f32x4*)(smem + FILM_OFF + ((3 * 64 + 4 * g + j) << 4));
        float pre = c[j] + fm.w;
        float z = fmaf(ctx, fm.x, fm.y);
        float s = __builtin_amdgcn_rcpf(1.0f + __builtin_amdgcn_exp2f(-z));
        float v = fmaf(ctx, fm.z, s * pre);
        if (g == 0) out[((size_t)b * NN + n) * 3 + j] = v;
      }
    }
  }
}

extern "C" void kernel_launch(void* const* d_in, const int* in_sizes, int n_in,
                              void* d_out, int out_size, void* d_ws, size_t ws_size,
                              hipStream_t stream) {
  const float* context = (const float*)d_in[0];  // (64, 8192)
  const float* y       = (const float*)d_in[1];  // (64, 8192, 3)
  const float* tnw     = (const float*)d_in[2];  // (64, 9356)
  float* out           = (float*)d_out;          // (64, 8192, 3)

  dim3 grid(NN / 128, BB, 1);  // 128 points per block (4 waves x 32 pts)
  dim3 block(256, 1, 1);
  ode_hypernet_kernel<<<grid, block, 0, stream>>>(context, y, tnw, out);
}

// Round 5
// 53.561 us; speedup vs baseline: 4.8640x; 1.1450x over previous
//
#include <hip/hip_runtime.h>
#include <math.h>

#define BB 64
#define NN 8192
#define TOTAL_W 9356

typedef _Float16 f16x8 __attribute__((ext_vector_type(8)));
typedef float f32x4 __attribute__((ext_vector_type(4)));
typedef float f32x2 __attribute__((ext_vector_type(2)));
typedef unsigned int u32x2 __attribute__((ext_vector_type(2)));

#define L2E 1.44269504088896340736f
#define LN2 0.6931471805599453f

// ---- LDS layout (bytes) ----
#define W0_OFF   0                      // f32 W0r[3][64] row-major (768 B used)
#define FILM_OFF 1024                   // f32 [4 layers][4 prm][64]; prm: 0=bias 1=wsc*L2E 2=bsc*L2E 3=wsh
#define A1_OFF   (FILM_OFF + 4096)      // A-frags L1: [m][t][lane] f16x8 = 8192 B
#define A2_OFF   (A1_OFF + 8192)
#define A3_OFF   (A2_OFF + 8192)        // 2048 B
#define ACT_OFF  (A3_OFF + 2048)        // Act[128 pts][16 x 8B], pair-level XOR swizzle
#define LDS_BYTES (ACT_OFF + 128*128)   // 39936

#define MFMA16(a, b, c) __builtin_amdgcn_mfma_f32_16x16x32_f16(a, b, c, 0, 0, 0)
#define EXP2 __builtin_amdgcn_exp2f
#define LOG2 __builtin_amdgcn_logf
#define RCPF __builtin_amdgcn_rcpf

__device__ __forceinline__ f32x2 pfma(f32x2 a, f32x2 b, f32x2 c) {
  return __builtin_elementwise_fma(a, b, c);
}

__device__ __forceinline__ f32x4 filmq(const unsigned char* smem, int l, int prm, int q) {
  return *(const f32x4*)(smem + FILM_OFF + (((l * 4 + prm) * 64 + q) << 2));
}

// FiLM (+softplus) on a D-quad for one point; returns 2x f16-pairs (8 B).
template<bool SP>
__device__ __forceinline__ u32x2 film_quad(f32x4 acc, float ctx,
                                           f32x4 wscq, f32x4 bscq, f32x4 wshq) {
  f32x2 ctx2 = {ctx, ctx};
  f32x2 one = {1.f, 1.f};
  f32x2 z0 = pfma(ctx2, (f32x2){wscq.x, wscq.y}, (f32x2){bscq.x, bscq.y});
  f32x2 z1 = pfma(ctx2, (f32x2){wscq.z, wscq.w}, (f32x2){bscq.z, bscq.w});
  f32x2 d0 = {EXP2(-z0.x), EXP2(-z0.y)};  d0 += one;
  f32x2 d1 = {EXP2(-z1.x), EXP2(-z1.y)};  d1 += one;
  f32x2 s0 = {RCPF(d0.x), RCPF(d0.y)};
  f32x2 s1 = {RCPF(d1.x), RCPF(d1.y)};
  f32x2 v0 = pfma(ctx2, (f32x2){wshq.x, wshq.y}, s0 * (f32x2){acc.x, acc.y});
  f32x2 v1 = pfma(ctx2, (f32x2){wshq.z, wshq.w}, s1 * (f32x2){acc.z, acc.w});
  if (SP) {  // softplus = LN2 * log2(1 + 2^(v*L2E))
    f32x2 l2 = {L2E, L2E}, ln = {LN2, LN2};
    f32x2 t0 = v0 * l2, t1 = v1 * l2;
    f32x2 u0 = {EXP2(t0.x), EXP2(t0.y)};  u0 += one;
    f32x2 u1 = {EXP2(t1.x), EXP2(t1.y)};  u1 += one;
    f32x2 g0 = {LOG2(u0.x), LOG2(u0.y)};
    f32x2 g1 = {LOG2(u1.x), LOG2(u1.y)};
    v0 = g0 * ln;
    v1 = g1 * ln;
  }
  auto p01 = __builtin_amdgcn_cvt_pkrtz(v0.x, v0.y);
  auto p23 = __builtin_amdgcn_cvt_pkrtz(v1.x, v1.y);
  u32x2 w;
  w.x = __builtin_bit_cast(unsigned int, p01);
  w.y = __builtin_bit_cast(unsigned int, p23);
  return w;
}

// slot s (4 feats each) stored at 8B-pos ((s>>1)^(pt&7))*2 | (s&1)
__device__ __forceinline__ void act_store(unsigned char* smem, int pt, int slot, u32x2 w) {
  int pos = ((((slot >> 1) ^ (pt & 7)) << 1) | (slot & 1));
  *(u32x2*)(smem + ACT_OFF + pt * 128 + (pos << 3)) = w;
}
// read 16B granule 'pair' (slots 2p,2p+1 = feats 8p..8p+7)
__device__ __forceinline__ f16x8 act_load(const unsigned char* smem, int pt, int pair) {
  int gr = pair ^ (pt & 7);
  return *(const f16x8*)(smem + ACT_OFF + pt * 128 + (gr << 4));
}

__global__ __launch_bounds__(256)
void ode_hypernet_kernel(const float* __restrict__ context,
                         const float* __restrict__ y,
                         const float* __restrict__ tnw,
                         float* __restrict__ out) {
  __shared__ __align__(16) unsigned char smem[LDS_BYTES];
  const int b = blockIdx.y;
  const int tid = threadIdx.x;
  const float* __restrict__ wb = tnw + (size_t)b * TOTAL_W;

  // ---------- staging ----------
  if (tid < 192) ((float*)(smem + W0_OFF))[tid] = wb[tid];  // W0 rows 3x64
  if (tid < 64) {
    const int biaso[4] = {192, 4544, 8896, 9344};
    const int dim[4] = {64, 64, 64, 3};
#pragma unroll
    for (int l = 0; l < 4; ++l) {
      float bv = 0.f, wscv = 0.f, bscv = 0.f, wshv = 0.f;
      if (tid < dim[l]) {
        int bo = biaso[l], d = dim[l];
        bv = wb[bo + tid];
        wscv = wb[bo + d + tid] * L2E;
        bscv = wb[bo + 2 * d + tid] * L2E;
        wshv = wb[bo + 3 * d + tid];
      }
      float* f = (float*)(smem + FILM_OFF) + l * 256;
      f[tid] = bv;
      f[64 + tid] = wscv;
      f[128 + tid] = bscv;
      f[192 + tid] = wshv;
    }
  }
  // A-fragments L1/L2 (A = W^T, 16x32 tiles)
#pragma unroll
  for (int L = 0; L < 2; ++L) {
    const int woff = L ? 4800 : 448;
    const int aoff = L ? A2_OFF : A1_OFF;
    for (int r = tid; r < 512; r += 256) {
      int lane_r = r & 63;
      int t = (r >> 6) & 1;
      int m = r >> 7;
      int f_out = 16 * m + (lane_r & 15);
      int f_in0 = 32 * t + 8 * (lane_r >> 4);
      f16x8 h;
#pragma unroll
      for (int i = 0; i < 8; ++i) h[i] = (_Float16)wb[woff + (f_in0 + i) * 64 + f_out];
      *(f16x8*)(smem + aoff + r * 16) = h;
    }
  }
  if (tid < 128) {  // A3: W3[f_in][3], rows>=3 zero
    int lane_r = tid & 63;
    int t = tid >> 6;
    int f_out = lane_r & 15;
    int f_in0 = 32 * t + 8 * (lane_r >> 4);
    f16x8 h;
#pragma unroll
    for (int i = 0; i < 8; ++i)
      h[i] = (f_out < 3) ? (_Float16)wb[9152 + (f_in0 + i) * 3 + f_out] : (_Float16)0.f;
    *(f16x8*)(smem + A3_OFF + tid * 16) = h;
  }
  __syncthreads();

  // ---------- per-wave main ----------
  const int lane = tid & 63;
  const int wid = tid >> 6;
  const int g = lane >> 4;
  const int col = lane & 15;
  const int pt0 = wid * 32 + col;
  const int pt1 = pt0 + 16;
  const int q4 = 4 * g;

#pragma unroll 1
  for (int half = 0; half < 2; ++half) {
    const int nbase = blockIdx.x * 256 + half * 128;
    const int n0 = nbase + pt0, n1 = nbase + pt1;
    const float ctx0 = context[(size_t)b * NN + n0];
    const float ctx1 = context[(size_t)b * NN + n1];
    const size_t yb0 = ((size_t)b * NN + n0) * 3;
    const size_t yb1 = ((size_t)b * NN + n1) * 3;
    const float y00 = y[yb0], y01 = y[yb0 + 1], y02 = y[yb0 + 2];
    const float y10 = y[yb1], y11 = y[yb1 + 1], y12 = y[yb1 + 2];

    // ----- layer 0 (3 -> 64), packed VALU, bias folded into acc init -----
#pragma unroll
    for (int m = 0; m < 4; ++m) {
      const int q = 16 * m + q4;
      f32x4 biasq = filmq(smem, 0, 0, q);
      f32x4 w0a = *(const f32x4*)(smem + W0_OFF + ((0 * 64 + q) << 2));
      f32x4 w0b = *(const f32x4*)(smem + W0_OFF + ((1 * 64 + q) << 2));
      f32x4 w0c = *(const f32x4*)(smem + W0_OFF + ((2 * 64 + q) << 2));
      f32x2 aLo, aHi, cLo, cHi;
      aLo = pfma((f32x2){y00, y00}, (f32x2){w0a.x, w0a.y}, (f32x2){biasq.x, biasq.y});
      aLo = pfma((f32x2){y01, y01}, (f32x2){w0b.x, w0b.y}, aLo);
      aLo = pfma((f32x2){y02, y02}, (f32x2){w0c.x, w0c.y}, aLo);
      aHi = pfma((f32x2){y00, y00}, (f32x2){w0a.z, w0a.w}, (f32x2){biasq.z, biasq.w});
      aHi = pfma((f32x2){y01, y01}, (f32x2){w0b.z, w0b.w}, aHi);
      aHi = pfma((f32x2){y02, y02}, (f32x2){w0c.z, w0c.w}, aHi);
      cLo = pfma((f32x2){y10, y10}, (f32x2){w0a.x, w0a.y}, (f32x2){biasq.x, biasq.y});
      cLo = pfma((f32x2){y11, y11}, (f32x2){w0b.x, w0b.y}, cLo);
      cLo = pfma((f32x2){y12, y12}, (f32x2){w0c.x, w0c.y}, cLo);
      cHi = pfma((f32x2){y10, y10}, (f32x2){w0a.z, w0a.w}, (f32x2){biasq.z, biasq.w});
      cHi = pfma((f32x2){y11, y11}, (f32x2){w0b.z, w0b.w}, cHi);
      cHi = pfma((f32x2){y12, y12}, (f32x2){w0c.z, w0c.w}, cHi);
      f32x4 acc0 = {aLo.x, aLo.y, aHi.x, aHi.y};
      f32x4 acc1 = {cLo.x, cLo.y, cHi.x, cHi.y};
      f32x4 wscq = filmq(smem, 0, 1, q);
      f32x4 bscq = filmq(smem, 0, 2, q);
      f32x4 wshq = filmq(smem, 0, 3, q);
      act_store(smem, pt0, 4 * m + g, film_quad<true>(acc0, ctx0, wscq, bscq, wshq));
      act_store(smem, pt1, 4 * m + g, film_quad<true>(acc1, ctx1, wscq, bscq, wshq));
    }

    // ----- layers 1,2 (64 -> 64) on MFMA -----
#pragma unroll
    for (int L = 1; L <= 2; ++L) {
      const int aoff = (L == 1) ? A1_OFF : A2_OFF;
      f16x8 B00 = act_load(smem, pt0, g);
      f16x8 B01 = act_load(smem, pt0, 4 + g);
      f16x8 B10 = act_load(smem, pt1, g);
      f16x8 B11 = act_load(smem, pt1, 4 + g);
#pragma unroll
      for (int m = 0; m < 4; ++m) {
        const int q = 16 * m + q4;
        f32x4 biasq = filmq(smem, L, 0, q);
        f16x8 a0 = *(const f16x8*)(smem + aoff + ((m * 2 + 0) * 64 + lane) * 16);
        f16x8 a1 = *(const f16x8*)(smem + aoff + ((m * 2 + 1) * 64 + lane) * 16);
        f32x4 c0 = biasq, c1 = biasq;
        c0 = MFMA16(a0, B00, c0);
        c0 = MFMA16(a1, B01, c0);
        c1 = MFMA16(a0, B10, c1);
        c1 = MFMA16(a1, B11, c1);
        f32x4 wscq = filmq(smem, L, 1, q);
        f32x4 bscq = filmq(smem, L, 2, q);
        f32x4 wshq = filmq(smem, L, 3, q);
        act_store(smem, pt0, 4 * m + g, film_quad<true>(c0, ctx0, wscq, bscq, wshq));
        act_store(smem, pt1, 4 * m + g, film_quad<true>(c1, ctx1, wscq, bscq, wshq));
      }
    }

    // ----- layer 3 (64 -> 3) on MFMA, FiLM only -----
    {
      f16x8 B00 = act_load(smem, pt0, g);
      f16x8 B01 = act_load(smem, pt0, 4 + g);
      f16x8 B10 = act_load(smem, pt1, g);
      f16x8 B11 = act_load(smem, pt1, 4 + g);
      f16x8 a0 = *(const f16x8*)(smem + A3_OFF + (0 * 64 + lane) * 16);
      f16x8 a1 = *(const f16x8*)(smem + A3_OFF + (1 * 64 + lane) * 16);
      f32x4 biasq = filmq(smem, 3, 0, q4);  // zeros beyond feat 2 (staged)
      f32x4 c0 = biasq, c1 = biasq;
      c0 = MFMA16(a0, B00, c0);
      c0 = MFMA16(a1, B01, c0);
      c1 = MFMA16(a0, B10, c1);
      c1 = MFMA16(a1, B11, c1);
      f32x4 wscq = filmq(smem, 3, 1, q4);
      f32x4 bscq = filmq(smem, 3, 2, q4);
      f32x4 wshq = filmq(smem, 3, 3, q4);
      if (g == 0) {
#pragma unroll
        for (int p = 0; p < 2; ++p) {
          f32x4 c = p ? c1 : c0;
          float ctx = p ? ctx1 : ctx0;
          int n = p ? n1 : n0;
#pragma unroll
          for (int j = 0; j < 3; ++j) {
            float z = fmaf(ctx, wscq[j], bscq[j]);
            float s = RCPF(1.0f + EXP2(-z));
            float v = fmaf(ctx, wshq[j], s * c[j]);
            out[((size_t)b * NN + n) * 3 + j] = v;
          }
        }
      }
    }
  }
}

extern "C" void kernel_launch(void* const* d_in, const int* in_sizes, int n_in,
                              void* d_out, int out_size, void* d_ws, size_t ws_size,
                              hipStream_t stream) {
  const float* context = (const float*)d_in[0];  // (64, 8192)
  const float* y       = (const float*)d_in[1];  // (64, 8192, 3)
  const float* tnw     = (const float*)d_in[2];  // (64, 9356)
  float* out           = (float*)d_out;          // (64, 8192, 3)

  dim3 grid(NN / 256, BB, 1);  // 2048 blocks, 256 points each (2 halves x 128)
  dim3 block(256, 1, 1);
  ode_hypernet_kernel<<<grid, block, 0, stream>>>(context, y, tnw, out);
}